// Round 8
// baseline (245.195 us; speedup 1.0000x reference)
//
#include <hip/hip_runtime.h>
#include <math.h>

#define HFD 128
#define WFD 128
#define DFD 512
#define KA  4
#define NA  (HFD*WFD*KA)      // 65536
#define MAXD 512
#define HID 1024
#define FIN 4608              // 3*3*512
#define CMAX 2048
#define NBUCK 1025
#define BINCAP 64
#define TAUF 0.5f
#define NMS_THR 0.3f

typedef __bf16 bf16x8 __attribute__((ext_vector_type(8)));
typedef float  floatx4 __attribute__((ext_vector_type(4)));

__device__ __forceinline__ unsigned short f2bf(float x) {
    unsigned u = __float_as_uint(x);
    unsigned r = (u + 0x7FFFu + ((u >> 16) & 1u)) >> 16;   // RNE
    return (unsigned short)r;
}

// ---- grid-wide front: score+bucket-bin (blocks 0..255) + transposes
__global__ __launch_bounds__(256)
void front_kernel(const float* __restrict__ rpn_obj,
                  unsigned* __restrict__ hist,
                  unsigned long long* __restrict__ bins,
                  const float* __restrict__ W1,
                  unsigned short* __restrict__ W1t,
                  const float* __restrict__ W2,
                  unsigned short* __restrict__ W2t) {
    __shared__ float tile[32][33];
    int b = blockIdx.x;
    if (b < 256) {
        int n = b * 256 + threadIdx.x;
        float2 o = ((const float2*)rpn_obj)[n];
        float m  = fmaxf(o.x, o.y);
        float e0 = expf(o.x - m), e1 = expf(o.y - m);
        float s  = e1 / (e0 + e1);
        if (s > TAUF) {
            unsigned bits = __float_as_uint(s);
            unsigned bk = (bits - 0x3F000000u) >> 13;     // 0..1024
            unsigned slot = atomicAdd(&hist[bk], 1u);
            if (slot < BINCAP)
                bins[bk * BINCAP + slot] =
                    ((unsigned long long)bits << 32) |
                    (unsigned long long)(~(unsigned)n);
        }
        return;
    }
    b -= 256;
    const float* W; unsigned short* Wt; int K, N;
    if (b < (FIN / 32) * (HID / 32)) { W = W1; Wt = W1t; K = FIN; N = HID; }
    else { b -= (FIN / 32) * (HID / 32); W = W2; Wt = W2t; K = HID; N = HID; }
    int bn = (b & (N / 32 - 1)) * 32;
    int bk = (b / (N / 32)) * 32;
    int tx = threadIdx.x & 31, ty = threadIdx.x >> 5;     // ty 0..7
#pragma unroll
    for (int r = 0; r < 32; r += 8)
        tile[ty + r][tx] = W[(long)(bk + ty + r) * N + bn + tx];
    __syncthreads();
#pragma unroll
    for (int r = 0; r < 32; r += 8)
        Wt[(long)(bn + ty + r) * K + bk + tx] = f2bf(tile[tx][ty + r]);
}

// ---- single block: threshold + parallel gather + sort + decode
__global__ __launch_bounds__(1024)
void tgs_kernel(const unsigned* __restrict__ hist,
                const unsigned long long* __restrict__ bins,
                const float* __restrict__ rpn_reg,
                const float* __restrict__ anchors,
                float* __restrict__ sel,          // 512 x float4
                float* __restrict__ top_score,    // 512
                unsigned* __restrict__ valid_g) { // 512
    __shared__ unsigned long long keys[CMAX];     // 16 KB
    __shared__ unsigned Hs[NBUCK];                // 4.1 KB
    __shared__ unsigned Ssc[1024];                // 4 KB
    __shared__ unsigned cntS;
    __shared__ unsigned thrS;

    int tid = threadIdx.x;
    int wave = tid >> 6, lane = tid & 63;

    // ---- phase A: load hist, suffix-sum buckets 1..1024, find threshold
    if (tid == 0) cntS = 0u;
    for (int i = tid; i < NBUCK; i += 1024) Hs[i] = hist[i];
    __syncthreads();
    unsigned sv = Hs[tid + 1];                    // thread t <-> bucket t+1
    Ssc[tid] = sv;
    __syncthreads();
    for (int d = 1; d < 1024; d <<= 1) {
        unsigned add = (tid + d < 1024) ? Ssc[tid + d] : 0u;
        __syncthreads();
        Ssc[tid] += add;
        __syncthreads();
    }
    if (tid == 0 && Ssc[0] < MAXD) thrS = 0u;
    {
        unsigned Scur = Ssc[tid];
        unsigned Snxt = (tid == 1023) ? 0u : Ssc[tid + 1];
        if (Scur >= MAXD && Snxt < MAXD) thrS = (unsigned)(tid + 1);
    }
    __syncthreads();
    unsigned thr = thrS;

    // ---- phase B: wave-per-bucket PARALLEL gather (lane i -> slot i)
    for (int b = (int)thr + wave; b < NBUCK; b += 16) {
        unsigned c = Hs[b]; if (c > BINCAP) c = BINCAP;
        unsigned base = 0;
        if (lane == 0 && c > 0) base = atomicAdd(&cntS, c);
        base = __shfl(base, 0);
        if (c > 0 && lane < c && base + lane < CMAX)
            keys[base + lane] = bins[(long)b * BINCAP + lane];
    }
    __syncthreads();
    unsigned cnt = cntS; if (cnt > CMAX) cnt = CMAX;
    int SN = (cnt <= 1024) ? 1024 : CMAX;
    for (int i = tid; i < SN; i += 1024)
        if (i >= (int)cnt) keys[i] = 0ULL;
    __syncthreads();

    // ---- phase C: bitonic sort descending over SN
    for (int k = 2; k <= SN; k <<= 1) {
        for (int j = k >> 1; j > 0; j >>= 1) {
            for (int i = tid; i < SN; i += 1024) {
                int ixj = i ^ j;
                if (ixj > i) {
                    unsigned long long a = keys[i], b = keys[ixj];
                    bool up = ((i & k) == 0);
                    if ((a < b) == up) { keys[i] = b; keys[ixj] = a; }
                }
            }
            __syncthreads();
        }
    }

    // ---- phase D: decode top-512 boxes (same fp32 formulas)
    if (tid < MAXD) {
        unsigned long long e = keys[tid];
        unsigned sbits = (unsigned)(e >> 32);
        bool v = (sbits != 0u);
        unsigned idx = v ? (unsigned)(~(unsigned)e) : 0u;
        int cell = idx >> 2, kk = idx & 3;
        float4 rg = *(const float4*)&rpn_reg[cell * 16 + 4 * kk];
        float4 an = *(const float4*)&anchors[idx * 4];
        float acx = an.x + an.z * 0.5f;
        float acy = an.y + an.w * 0.5f;
        float cx = acx + rg.x * an.z;
        float cy = acy + rg.y * an.w;
        float w  = an.z * expf(rg.z);
        float h  = an.w * expf(rg.w);
        ((float4*)sel)[tid] = make_float4(cx - 0.5f * w, cy - 0.5f * h, w, h);
        top_score[tid] = v ? __uint_as_float(sbits) : 0.0f;
        valid_g[tid]   = v ? 1u : 0u;
    }
}

// ---------------------------------------------------- IoU bitmask
__global__ __launch_bounds__(512)
void iou_mask_kernel(const float* __restrict__ sel,
                     unsigned long long* __restrict__ mask) {
    int i = blockIdx.x;
    int j = threadIdx.x;
    float4 bi = ((const float4*)sel)[i];
    float4 bj = ((const float4*)sel)[j];
    float x2i = bi.x + bi.z, y2i = bi.y + bi.w;
    float x2j = bj.x + bj.z, y2j = bj.y + bj.w;
    float ai = bi.z * bi.w, aj = bj.z * bj.w;
    float ix = fmaxf(0.0f, fminf(x2i, x2j) - fmaxf(bi.x, bj.x));
    float iy = fmaxf(0.0f, fminf(y2i, y2j) - fmaxf(bi.y, bj.y));
    float inter = ix * iy;
    float iou = inter / (ai + aj - inter + 1e-8f);
    unsigned long long bal = __ballot(iou > NMS_THR);
    if ((j & 63) == 0) mask[i * 8 + (j >> 6)] = bal;
}

// -------- sequential NMS (ctz-skip) + kept-row compaction (1 wave)
__global__ __launch_bounds__(64)
void nms_scan_kernel(const unsigned long long* __restrict__ mask,
                     const unsigned* __restrict__ valid,
                     unsigned* __restrict__ cidx,
                     unsigned* __restrict__ nkeep) {
    int lane = threadIdx.x;
    unsigned long long w[8][8];   // [g][t<=g] : mask word t of row 64g+lane
#pragma unroll
    for (int g = 0; g < 8; ++g)
#pragma unroll
        for (int t = 0; t < 8; ++t)
            if (t <= g) w[g][t] = mask[(g * 64 + lane) * 8 + t];
    unsigned long long vb[8];
#pragma unroll
    for (int g = 0; g < 8; ++g)
        vb[g] = __ballot(valid[g * 64 + lane] != 0u);

    unsigned long long keepw[8];
#pragma unroll
    for (int g = 0; g < 8; ++g) {
        bool pre = false;
#pragma unroll
        for (int t = 0; t < 8; ++t)
            if (t < g) pre = pre || ((w[g][t] & keepw[t]) != 0ULL);
        unsigned long long alive = vb[g] & ~__ballot(pre);
        unsigned long long intra = w[g][g];
        unsigned long long kg = 0ULL;
        while (alive) {                       // once per KEPT box
            int b = __builtin_ctzll(alive);
            unsigned long long bit = 1ULL << b;
            kg |= bit;
            unsigned long long sup = __ballot((intra >> b) & 1ULL);
            alive &= ~(sup | bit);
        }
        keepw[g] = kg;
    }
    // compaction: cidx[pos] = original row, for kept rows in ascending order
    unsigned total = 0;
#pragma unroll
    for (int g = 0; g < 8; ++g) {
        unsigned long long kg = keepw[g];     // wave-uniform
        if ((kg >> lane) & 1ULL) {
            unsigned pos = total +
                (unsigned)__builtin_popcountll(kg & ((1ULL << lane) - 1ULL));
            cidx[pos] = (unsigned)(g * 64 + lane);
        }
        total += (unsigned)__builtin_popcountll(kg);
    }
    if (lane == 0) nkeep[0] = total;
}

// ----------------- ROI align, compacted rows only (bf16 output)
__global__ __launch_bounds__(256)
void roialign_kernel(const float* __restrict__ feat,
                     const float* __restrict__ sel,
                     const unsigned* __restrict__ cidx,
                     const unsigned* __restrict__ nkeep,
                     unsigned short* __restrict__ pooled) {
    int m = blockIdx.x;
    if (m >= (int)nkeep[0]) return;           // uniform early-exit
    int mrow = (int)cidx[m];
    int c = threadIdx.x;                      // channels c and c+256
    float4 b = ((const float4*)sel)[mrow];
    float bx = b.x, by = b.y, bw = b.z, bh = b.w;
    float vmax0[9], vmax1[9];
#pragma unroll
    for (int t = 0; t < 9; ++t) { vmax0[t] = -INFINITY; vmax1[t] = -INFINITY; }
#pragma unroll
    for (int p = 0; p < 6; ++p) {
        float fy = (by + ((float)p + 0.5f) / 6.0f * bh) / 16.0f - 0.5f;
        fy = fminf(fmaxf(fy, 0.0f), 127.0f);
        int y0 = (int)floorf(fy);
        int y1 = min(y0 + 1, 127);
        float wy = fy - (float)y0;
#pragma unroll
        for (int q = 0; q < 6; ++q) {
            float fx = (bx + ((float)q + 0.5f) / 6.0f * bw) / 16.0f - 0.5f;
            fx = fminf(fmaxf(fx, 0.0f), 127.0f);
            int x0 = (int)floorf(fx);
            int x1 = min(x0 + 1, 127);
            float wx = fx - (float)x0;
            const float* f00 = feat + (y0 * WFD + x0) * DFD;
            const float* f01 = feat + (y0 * WFD + x1) * DFD;
            const float* f10 = feat + (y1 * WFD + x0) * DFD;
            const float* f11 = feat + (y1 * WFD + x1) * DFD;
            float w00 = (1.0f - wy) * (1.0f - wx);
            float w01 = (1.0f - wy) * wx;
            float w10 = wy * (1.0f - wx);
            float w11 = wy * wx;
            int t = (p >> 1) * 3 + (q >> 1);
            float v0 = f00[c] * w00 + f01[c] * w01 + f10[c] * w10 + f11[c] * w11;
            float v1 = f00[c + 256] * w00 + f01[c + 256] * w01 +
                       f10[c + 256] * w10 + f11[c + 256] * w11;
            vmax0[t] = fmaxf(vmax0[t], v0);
            vmax1[t] = fmaxf(vmax1[t], v1);
        }
    }
#pragma unroll
    for (int t = 0; t < 9; ++t) {
        pooled[m * FIN + t * DFD + c] = f2bf(vmax0[t]);
        pooled[m * FIN + t * DFD + c + 256] = f2bf(vmax1[t]);
    }
}

// ------- bf16 MFMA GEMM, no split-K, fused bias+relu epilogue.
// A: M x K bf16; Bt: N x K bf16. Out either bf16 or fp32 (one non-null).
// Blocks whose 64-row stripe is past nkeep exit immediately.
#define LDSTRIDE 40
__global__ __launch_bounds__(256)
void gemm_fused_kernel(const unsigned short* __restrict__ A,
                       const unsigned short* __restrict__ Bt,
                       const float* __restrict__ bias,
                       unsigned short* __restrict__ out_bf,
                       float* __restrict__ out_f,
                       const unsigned* __restrict__ nkeep,
                       int N, int K) {
    int bm = blockIdx.y * 64;
    if (bm >= (int)nkeep[0]) return;          // uniform early-exit
    __shared__ unsigned short As[64 * LDSTRIDE];
    __shared__ unsigned short Bs[64 * LDSTRIDE];
    int tid = threadIdx.x;
    int wave = tid >> 6, lane = tid & 63;
    int bn = blockIdx.x * 64;

    floatx4 acc[4] = {};
    int lr = tid >> 2;            // 0..63  staging row
    int lk = (tid & 3) << 3;      // 0,8,16,24  staging k-offset
    int frow = lane & 15, quad = lane >> 4;

    const unsigned short* Ap = A + (long)(bm + lr) * K + lk;
    const unsigned short* Bp = Bt + (long)(bn + lr) * K + lk;

    for (int k0 = 0; k0 < K; k0 += 32) {
        uint4 av = *(const uint4*)(Ap + k0);
        uint4 bv = *(const uint4*)(Bp + k0);
        *(uint4*)&As[lr * LDSTRIDE + lk] = av;
        *(uint4*)&Bs[lr * LDSTRIDE + lk] = bv;
        __syncthreads();
        bf16x8 af = *(const bf16x8*)&As[(wave * 16 + frow) * LDSTRIDE + quad * 8];
#pragma unroll
        for (int t = 0; t < 4; ++t) {
            bf16x8 bfv = *(const bf16x8*)&Bs[(t * 16 + frow) * LDSTRIDE + quad * 8];
            acc[t] = __builtin_amdgcn_mfma_f32_16x16x32_bf16(af, bfv, acc[t], 0, 0, 0);
        }
        __syncthreads();
    }

#pragma unroll
    for (int t = 0; t < 4; ++t) {
        int n = bn + t * 16 + frow;
        float bv = bias[n];
#pragma unroll
        for (int r = 0; r < 4; ++r) {
            int m = bm + wave * 16 + quad * 4 + r;
            float v = fmaxf(acc[t][r] + bv, 0.0f);
            if (out_bf) out_bf[(long)m * N + n] = f2bf(v);
            else        out_f[(long)m * N + n]  = v;
        }
    }
}

// --- compacted rows: W3 dot over h2 row + refine epilogue, scatter
__global__ __launch_bounds__(256)
void rowhead_kernel(const float* __restrict__ h2,
                    const float* __restrict__ W3,
                    const float* __restrict__ b3,
                    const float* __restrict__ sel,
                    const float* __restrict__ top_score,
                    const unsigned* __restrict__ cidx,
                    const unsigned* __restrict__ nkeep,
                    float* __restrict__ out) {
    int p = blockIdx.x;
    if (p >= (int)nkeep[0]) return;           // out pre-zeroed by memset
    __shared__ float red[4][4];
    int t = threadIdx.x;
    int wave = t >> 6, lane = t & 63;
    int c = t * 4;
    float4 s = *(const float4*)&h2[(long)p * HID + c];
    float h[4] = {s.x, s.y, s.z, s.w};        // already bias+relu'd
    float a0 = 0.f, a1 = 0.f, a2 = 0.f, a3 = 0.f;
#pragma unroll
    for (int i = 0; i < 4; ++i) {
        float4 w = *(const float4*)&W3[(c + i) * 4];
        a0 += h[i] * w.x; a1 += h[i] * w.y;
        a2 += h[i] * w.z; a3 += h[i] * w.w;
    }
#pragma unroll
    for (int off = 32; off > 0; off >>= 1) {
        a0 += __shfl_down(a0, off);
        a1 += __shfl_down(a1, off);
        a2 += __shfl_down(a2, off);
        a3 += __shfl_down(a3, off);
    }
    if (lane == 0) {
        red[wave][0] = a0; red[wave][1] = a1;
        red[wave][2] = a2; red[wave][3] = a3;
    }
    __syncthreads();
    if (t == 0) {
        int r = (int)cidx[p];
        float d0 = red[0][0] + red[1][0] + red[2][0] + red[3][0] + b3[0];
        float d1 = red[0][1] + red[1][1] + red[2][1] + red[3][1] + b3[1];
        float d2 = red[0][2] + red[1][2] + red[2][2] + red[3][2] + b3[2];
        float d3 = red[0][3] + red[1][3] + red[2][3] + red[3][3] + b3[3];
        float4 b = ((const float4*)sel)[r];
        float acx = b.x + 0.5f * b.z;
        float acy = b.y + 0.5f * b.w;
        float cx = acx + d0 * b.z;
        float cy = acy + d1 * b.w;
        float nw = b.z * expf(d2);
        float nh = b.w * expf(d3);
        out[r * 5 + 0] = cx - 0.5f * nw;
        out[r * 5 + 1] = cy - 0.5f * nh;
        out[r * 5 + 2] = nw;
        out[r * 5 + 3] = nh;
        out[r * 5 + 4] = top_score[r];        // kept implies valid
    }
}

// ---------------------------------------------------------------- host
extern "C" void kernel_launch(void* const* d_in, const int* in_sizes, int n_in,
                              void* d_out, int out_size, void* d_ws, size_t ws_size,
                              hipStream_t stream) {
    const float* features = (const float*)d_in[0];
    const float* rpn_obj  = (const float*)d_in[1];
    const float* rpn_reg  = (const float*)d_in[2];
    const float* anchors  = (const float*)d_in[3];
    const float* W1 = (const float*)d_in[4];
    const float* b1 = (const float*)d_in[5];
    const float* W2 = (const float*)d_in[6];
    const float* b2 = (const float*)d_in[7];
    const float* W3 = (const float*)d_in[8];
    const float* b3 = (const float*)d_in[9];
    float* out = (float*)d_out;

    char* ws = (char*)d_ws;
    size_t off = 0;
    auto alloc = [&](size_t bytes) {
        char* p = ws + off;
        off += (bytes + 255) & ~(size_t)255;
        return p;
    };
    unsigned* hist      = (unsigned*)alloc(NBUCK * sizeof(unsigned));
    unsigned long long* bins =
        (unsigned long long*)alloc((size_t)NBUCK * BINCAP * 8);
    float*    sel       = (float*)alloc(MAXD * 4 * sizeof(float));
    float*    top_score = (float*)alloc(MAXD * sizeof(float));
    unsigned* valid     = (unsigned*)alloc(MAXD * sizeof(unsigned));
    unsigned* cidx      = (unsigned*)alloc(MAXD * sizeof(unsigned));
    unsigned* nkeep     = (unsigned*)alloc(sizeof(unsigned));
    unsigned long long* mask = (unsigned long long*)alloc(MAXD * 8 * 8);
    unsigned short* pooled = (unsigned short*)alloc((size_t)MAXD * FIN * 2);
    unsigned short* W1t = (unsigned short*)alloc((size_t)FIN * HID * 2);
    unsigned short* W2t = (unsigned short*)alloc((size_t)HID * HID * 2);
    unsigned short* h1  = (unsigned short*)alloc((size_t)MAXD * HID * 2);
    float*    h2        = (float*)alloc((size_t)MAXD * HID * sizeof(float));
    (void)ws_size; (void)in_sizes; (void)n_in;

    hipMemsetAsync(hist, 0, NBUCK * sizeof(unsigned), stream);
    hipMemsetAsync(out, 0, (size_t)out_size * sizeof(float), stream);

    const int TBLOCKS = (FIN / 32) * (HID / 32) + (HID / 32) * (HID / 32);
    front_kernel<<<256 + TBLOCKS, 256, 0, stream>>>(rpn_obj, hist, bins,
                                                    W1, W1t, W2, W2t);
    tgs_kernel<<<1, 1024, 0, stream>>>(hist, bins, rpn_reg, anchors,
                                       sel, top_score, valid);
    iou_mask_kernel<<<MAXD, 512, 0, stream>>>(sel, mask);
    nms_scan_kernel<<<1, 64, 0, stream>>>(mask, valid, cidx, nkeep);
    roialign_kernel<<<MAXD, 256, 0, stream>>>(features, sel, cidx, nkeep,
                                              pooled);
    // GEMM1: pooled(P x 4608) @ W1 + b1, relu -> h1 bf16
    gemm_fused_kernel<<<dim3(HID / 64, MAXD / 64), 256, 0, stream>>>(
        pooled, W1t, b1, h1, (float*)nullptr, nkeep, HID, FIN);
    // GEMM2: h1(P x 1024) @ W2 + b2, relu -> h2 fp32
    gemm_fused_kernel<<<dim3(HID / 64, MAXD / 64), 256, 0, stream>>>(
        h1, W2t, b2, (unsigned short*)nullptr, h2, nkeep, HID, HID);
    rowhead_kernel<<<MAXD, 256, 0, stream>>>(h2, W3, b3, sel, top_score,
                                             cidx, nkeep, out);
}

// Round 9
// 201.639 us; speedup vs baseline: 1.2160x; 1.2160x over previous
//
#include <hip/hip_runtime.h>
#include <math.h>

#define HFD 128
#define WFD 128
#define DFD 512
#define KA  4
#define NA  (HFD*WFD*KA)      // 65536
#define MAXD 512
#define HID 1024
#define FIN 4608              // 3*3*512
#define CMAX 2048
#define NBUCK 1025
#define BINCAP 64
#define TAUF 0.5f
#define NMS_THR 0.3f
#define SPLITK 8

typedef __bf16 bf16x8 __attribute__((ext_vector_type(8)));
typedef float  floatx4 __attribute__((ext_vector_type(4)));

__device__ __forceinline__ unsigned short f2bf(float x) {
    unsigned u = __float_as_uint(x);
    unsigned r = (u + 0x7FFFu + ((u >> 16) & 1u)) >> 16;   // RNE
    return (unsigned short)r;
}

// ---- grid-wide front: score+bucket-bin (blocks 0..255) + transposes
__global__ __launch_bounds__(256)
void front_kernel(const float* __restrict__ rpn_obj,
                  unsigned* __restrict__ hist,
                  unsigned long long* __restrict__ bins,
                  const float* __restrict__ W1,
                  unsigned short* __restrict__ W1t,
                  const float* __restrict__ W2,
                  unsigned short* __restrict__ W2t) {
    __shared__ float tile[32][33];
    int b = blockIdx.x;
    if (b < 256) {
        int n = b * 256 + threadIdx.x;
        float2 o = ((const float2*)rpn_obj)[n];
        float m  = fmaxf(o.x, o.y);
        float e0 = expf(o.x - m), e1 = expf(o.y - m);
        float s  = e1 / (e0 + e1);
        if (s > TAUF) {
            unsigned bits = __float_as_uint(s);
            unsigned bk = (bits - 0x3F000000u) >> 13;     // 0..1024
            unsigned slot = atomicAdd(&hist[bk], 1u);
            if (slot < BINCAP)
                bins[bk * BINCAP + slot] =
                    ((unsigned long long)bits << 32) |
                    (unsigned long long)(~(unsigned)n);
        }
        return;
    }
    b -= 256;
    const float* W; unsigned short* Wt; int K, N;
    if (b < (FIN / 32) * (HID / 32)) { W = W1; Wt = W1t; K = FIN; N = HID; }
    else { b -= (FIN / 32) * (HID / 32); W = W2; Wt = W2t; K = HID; N = HID; }
    int bn = (b & (N / 32 - 1)) * 32;
    int bk = (b / (N / 32)) * 32;
    int tx = threadIdx.x & 31, ty = threadIdx.x >> 5;     // ty 0..7
#pragma unroll
    for (int r = 0; r < 32; r += 8)
        tile[ty + r][tx] = W[(long)(bk + ty + r) * N + bn + tx];
    __syncthreads();
#pragma unroll
    for (int r = 0; r < 32; r += 8)
        Wt[(long)(bn + ty + r) * K + bk + tx] = f2bf(tile[tx][ty + r]);
}

// ---- single block: threshold + parallel gather + sort + decode
__global__ __launch_bounds__(1024)
void tgs_kernel(const unsigned* __restrict__ hist,
                const unsigned long long* __restrict__ bins,
                const float* __restrict__ rpn_reg,
                const float* __restrict__ anchors,
                float* __restrict__ sel,          // 512 x float4
                float* __restrict__ top_score,    // 512
                unsigned* __restrict__ valid_g) { // 512
    __shared__ unsigned long long keys[CMAX];     // 16 KB
    __shared__ unsigned Hs[NBUCK];                // 4.1 KB
    __shared__ unsigned Ssc[1024];                // 4 KB
    __shared__ unsigned cntS;
    __shared__ unsigned thrS;

    int tid = threadIdx.x;
    int wave = tid >> 6, lane = tid & 63;

    // ---- phase A: load hist, suffix-sum buckets 1..1024, find threshold
    if (tid == 0) cntS = 0u;
    for (int i = tid; i < NBUCK; i += 1024) Hs[i] = hist[i];
    __syncthreads();
    unsigned sv = Hs[tid + 1];                    // thread t <-> bucket t+1
    Ssc[tid] = sv;
    __syncthreads();
    for (int d = 1; d < 1024; d <<= 1) {
        unsigned add = (tid + d < 1024) ? Ssc[tid + d] : 0u;
        __syncthreads();
        Ssc[tid] += add;
        __syncthreads();
    }
    if (tid == 0 && Ssc[0] < MAXD) thrS = 0u;
    {
        unsigned Scur = Ssc[tid];
        unsigned Snxt = (tid == 1023) ? 0u : Ssc[tid + 1];
        if (Scur >= MAXD && Snxt < MAXD) thrS = (unsigned)(tid + 1);
    }
    __syncthreads();
    unsigned thr = thrS;

    // ---- phase B: wave-per-bucket PARALLEL gather (lane i -> slot i)
    for (int b = (int)thr + wave; b < NBUCK; b += 16) {
        unsigned c = Hs[b]; if (c > BINCAP) c = BINCAP;
        unsigned base = 0;
        if (lane == 0 && c > 0) base = atomicAdd(&cntS, c);
        base = __shfl(base, 0);
        if (c > 0 && lane < c && base + lane < CMAX)
            keys[base + lane] = bins[(long)b * BINCAP + lane];
    }
    __syncthreads();
    unsigned cnt = cntS; if (cnt > CMAX) cnt = CMAX;
    int SN = (cnt <= 1024) ? 1024 : CMAX;
    for (int i = tid; i < SN; i += 1024)
        if (i >= (int)cnt) keys[i] = 0ULL;
    __syncthreads();

    // ---- phase C: bitonic sort descending over SN
    for (int k = 2; k <= SN; k <<= 1) {
        for (int j = k >> 1; j > 0; j >>= 1) {
            for (int i = tid; i < SN; i += 1024) {
                int ixj = i ^ j;
                if (ixj > i) {
                    unsigned long long a = keys[i], b = keys[ixj];
                    bool up = ((i & k) == 0);
                    if ((a < b) == up) { keys[i] = b; keys[ixj] = a; }
                }
            }
            __syncthreads();
        }
    }

    // ---- phase D: decode top-512 boxes (same fp32 formulas)
    if (tid < MAXD) {
        unsigned long long e = keys[tid];
        unsigned sbits = (unsigned)(e >> 32);
        bool v = (sbits != 0u);
        unsigned idx = v ? (unsigned)(~(unsigned)e) : 0u;
        int cell = idx >> 2, kk = idx & 3;
        float4 rg = *(const float4*)&rpn_reg[cell * 16 + 4 * kk];
        float4 an = *(const float4*)&anchors[idx * 4];
        float acx = an.x + an.z * 0.5f;
        float acy = an.y + an.w * 0.5f;
        float cx = acx + rg.x * an.z;
        float cy = acy + rg.y * an.w;
        float w  = an.z * expf(rg.z);
        float h  = an.w * expf(rg.w);
        ((float4*)sel)[tid] = make_float4(cx - 0.5f * w, cy - 0.5f * h, w, h);
        top_score[tid] = v ? __uint_as_float(sbits) : 0.0f;
        valid_g[tid]   = v ? 1u : 0u;
    }
}

// ---------------------------------------------------- IoU bitmask
__global__ __launch_bounds__(512)
void iou_mask_kernel(const float* __restrict__ sel,
                     unsigned long long* __restrict__ mask) {
    int i = blockIdx.x;
    int j = threadIdx.x;
    float4 bi = ((const float4*)sel)[i];
    float4 bj = ((const float4*)sel)[j];
    float x2i = bi.x + bi.z, y2i = bi.y + bi.w;
    float x2j = bj.x + bj.z, y2j = bj.y + bj.w;
    float ai = bi.z * bi.w, aj = bj.z * bj.w;
    float ix = fmaxf(0.0f, fminf(x2i, x2j) - fmaxf(bi.x, bj.x));
    float iy = fmaxf(0.0f, fminf(y2i, y2j) - fmaxf(bi.y, bj.y));
    float inter = ix * iy;
    float iou = inter / (ai + aj - inter + 1e-8f);
    unsigned long long bal = __ballot(iou > NMS_THR);
    if ((j & 63) == 0) mask[i * 8 + (j >> 6)] = bal;
}

// -------- sequential NMS (ctz-skip) + kept-row compaction (1 wave)
__global__ __launch_bounds__(64)
void nms_scan_kernel(const unsigned long long* __restrict__ mask,
                     const unsigned* __restrict__ valid,
                     unsigned* __restrict__ cidx,
                     unsigned* __restrict__ nkeep) {
    int lane = threadIdx.x;
    unsigned long long w[8][8];   // [g][t<=g] : mask word t of row 64g+lane
#pragma unroll
    for (int g = 0; g < 8; ++g)
#pragma unroll
        for (int t = 0; t < 8; ++t)
            if (t <= g) w[g][t] = mask[(g * 64 + lane) * 8 + t];
    unsigned long long vb[8];
#pragma unroll
    for (int g = 0; g < 8; ++g)
        vb[g] = __ballot(valid[g * 64 + lane] != 0u);

    unsigned long long keepw[8];
#pragma unroll
    for (int g = 0; g < 8; ++g) {
        bool pre = false;
#pragma unroll
        for (int t = 0; t < 8; ++t)
            if (t < g) pre = pre || ((w[g][t] & keepw[t]) != 0ULL);
        unsigned long long alive = vb[g] & ~__ballot(pre);
        unsigned long long intra = w[g][g];
        unsigned long long kg = 0ULL;
        while (alive) {                       // once per KEPT box
            int b = __builtin_ctzll(alive);
            unsigned long long bit = 1ULL << b;
            kg |= bit;
            unsigned long long sup = __ballot((intra >> b) & 1ULL);
            alive &= ~(sup | bit);
        }
        keepw[g] = kg;
    }
    // compaction: cidx[pos] = original row, kept rows ascending
    unsigned total = 0;
#pragma unroll
    for (int g = 0; g < 8; ++g) {
        unsigned long long kg = keepw[g];     // wave-uniform
        if ((kg >> lane) & 1ULL) {
            unsigned pos = total +
                (unsigned)__builtin_popcountll(kg & ((1ULL << lane) - 1ULL));
            cidx[pos] = (unsigned)(g * 64 + lane);
        }
        total += (unsigned)__builtin_popcountll(kg);
    }
    if (lane == 0) nkeep[0] = total;
}

// ----------------- ROI align, compacted rows only (bf16 output)
__global__ __launch_bounds__(256)
void roialign_kernel(const float* __restrict__ feat,
                     const float* __restrict__ sel,
                     const unsigned* __restrict__ cidx,
                     const unsigned* __restrict__ nkeep,
                     unsigned short* __restrict__ pooled) {
    int m = blockIdx.x;
    if (m >= (int)nkeep[0]) return;           // uniform early-exit
    int mrow = (int)cidx[m];
    int c = threadIdx.x;                      // channels c and c+256
    float4 b = ((const float4*)sel)[mrow];
    float bx = b.x, by = b.y, bw = b.z, bh = b.w;
    float vmax0[9], vmax1[9];
#pragma unroll
    for (int t = 0; t < 9; ++t) { vmax0[t] = -INFINITY; vmax1[t] = -INFINITY; }
#pragma unroll
    for (int p = 0; p < 6; ++p) {
        float fy = (by + ((float)p + 0.5f) / 6.0f * bh) / 16.0f - 0.5f;
        fy = fminf(fmaxf(fy, 0.0f), 127.0f);
        int y0 = (int)floorf(fy);
        int y1 = min(y0 + 1, 127);
        float wy = fy - (float)y0;
#pragma unroll
        for (int q = 0; q < 6; ++q) {
            float fx = (bx + ((float)q + 0.5f) / 6.0f * bw) / 16.0f - 0.5f;
            fx = fminf(fmaxf(fx, 0.0f), 127.0f);
            int x0 = (int)floorf(fx);
            int x1 = min(x0 + 1, 127);
            float wx = fx - (float)x0;
            const float* f00 = feat + (y0 * WFD + x0) * DFD;
            const float* f01 = feat + (y0 * WFD + x1) * DFD;
            const float* f10 = feat + (y1 * WFD + x0) * DFD;
            const float* f11 = feat + (y1 * WFD + x1) * DFD;
            float w00 = (1.0f - wy) * (1.0f - wx);
            float w01 = (1.0f - wy) * wx;
            float w10 = wy * (1.0f - wx);
            float w11 = wy * wx;
            int t = (p >> 1) * 3 + (q >> 1);
            float v0 = f00[c] * w00 + f01[c] * w01 + f10[c] * w10 + f11[c] * w11;
            float v1 = f00[c + 256] * w00 + f01[c + 256] * w01 +
                       f10[c + 256] * w10 + f11[c + 256] * w11;
            vmax0[t] = fmaxf(vmax0[t], v0);
            vmax1[t] = fmaxf(vmax1[t], v1);
        }
    }
#pragma unroll
    for (int t = 0; t < 9; ++t) {
        pooled[m * FIN + t * DFD + c] = f2bf(vmax0[t]);
        pooled[m * FIN + t * DFD + c + 256] = f2bf(vmax1[t]);
    }
}

// --------- bf16 MFMA GEMM, split-K (short critical path), compacted
// A: M x K bf16; Bt: N x K bf16. Cpart[z][M][N] fp32 partials.
// Split-K=8 keeps the barrier-separated K-loop to ~K/256 iterations —
// the R8 no-split version exposed 144 serial HBM latencies (54 µs).
#define LDSTRIDE 40
__global__ __launch_bounds__(256)
void mfma_gemm_kernel(const unsigned short* __restrict__ A,
                      const unsigned short* __restrict__ Bt,
                      float* __restrict__ Cpart,
                      const unsigned* __restrict__ nkeep,
                      int M, int N, int K) {
    int bm = blockIdx.y * 64;
    if (bm >= (int)nkeep[0]) return;          // uniform early-exit
    __shared__ unsigned short As[64 * LDSTRIDE];
    __shared__ unsigned short Bs[64 * LDSTRIDE];
    int tid = threadIdx.x;
    int wave = tid >> 6, lane = tid & 63;
    int bn = blockIdx.x * 64;
    int KC = K / SPLITK;
    int ks = blockIdx.z * KC;

    floatx4 acc[4] = {};
    int lr = tid >> 2;            // 0..63  staging row
    int lk = (tid & 3) << 3;      // 0,8,16,24  staging k-offset
    int frow = lane & 15, quad = lane >> 4;

    const unsigned short* Ap = A + (long)(bm + lr) * K + lk;
    const unsigned short* Bp = Bt + (long)(bn + lr) * K + lk;

    for (int k0 = ks; k0 < ks + KC; k0 += 32) {
        uint4 av = *(const uint4*)(Ap + k0);
        uint4 bv = *(const uint4*)(Bp + k0);
        *(uint4*)&As[lr * LDSTRIDE + lk] = av;
        *(uint4*)&Bs[lr * LDSTRIDE + lk] = bv;
        __syncthreads();
        bf16x8 af = *(const bf16x8*)&As[(wave * 16 + frow) * LDSTRIDE + quad * 8];
#pragma unroll
        for (int t = 0; t < 4; ++t) {
            bf16x8 bfv = *(const bf16x8*)&Bs[(t * 16 + frow) * LDSTRIDE + quad * 8];
            acc[t] = __builtin_amdgcn_mfma_f32_16x16x32_bf16(af, bfv, acc[t], 0, 0, 0);
        }
        __syncthreads();
    }

    float* Cp = Cpart + (long)blockIdx.z * M * N;
#pragma unroll
    for (int t = 0; t < 4; ++t) {
#pragma unroll
        for (int r = 0; r < 4; ++r) {
            int m = bm + wave * 16 + quad * 4 + r;
            int n = bn + t * 16 + frow;
            Cp[(long)m * N + n] = acc[t][r];
        }
    }
}

// --------------------- split-K reduce + bias + relu -> bf16 (rows < nkeep)
__global__ __launch_bounds__(256)
void reduce_bias_relu_kernel(const float* __restrict__ Cpart,
                             const float* __restrict__ bias,
                             unsigned short* __restrict__ out_bf,
                             const unsigned* __restrict__ nkeep,
                             int MN, int N) {
    int i4 = (blockIdx.x * blockDim.x + threadIdx.x) * 4;
    if (i4 >= MN) return;
    if ((unsigned)(i4 >> 10) >= nkeep[0]) return;   // row >= P (N==1024)
    float4 s = *(const float4*)&Cpart[i4];
#pragma unroll
    for (int z = 1; z < SPLITK; ++z) {
        float4 p = *(const float4*)&Cpart[(long)z * MN + i4];
        s.x += p.x; s.y += p.y; s.z += p.z; s.w += p.w;
    }
    int n = i4 & (N - 1);
    float4 bi = *(const float4*)&bias[n];
    s.x = fmaxf(s.x + bi.x, 0.0f);
    s.y = fmaxf(s.y + bi.y, 0.0f);
    s.z = fmaxf(s.z + bi.z, 0.0f);
    s.w = fmaxf(s.w + bi.w, 0.0f);
    uint2 o;
    o.x = (unsigned)f2bf(s.x) | ((unsigned)f2bf(s.y) << 16);
    o.y = (unsigned)f2bf(s.z) | ((unsigned)f2bf(s.w) << 16);
    *(uint2*)&out_bf[i4] = o;
}

// --- compacted rows: split-K reduce (GEMM2) + b2 + relu + W3 + epilogue
__global__ __launch_bounds__(256)
void rowhead_kernel(const float* __restrict__ Cpart,
                    const float* __restrict__ b2,
                    const float* __restrict__ W3,
                    const float* __restrict__ b3,
                    const float* __restrict__ sel,
                    const float* __restrict__ top_score,
                    const unsigned* __restrict__ cidx,
                    const unsigned* __restrict__ nkeep,
                    float* __restrict__ out) {
    int p = blockIdx.x;
    if (p >= (int)nkeep[0]) return;           // out pre-zeroed by memset
    __shared__ float red[4][4];
    int t = threadIdx.x;
    int wave = t >> 6, lane = t & 63;
    int c = t * 4;
    const int MN = MAXD * HID;
    float4 s = *(const float4*)&Cpart[(long)p * HID + c];
#pragma unroll
    for (int z = 1; z < SPLITK; ++z) {
        float4 q = *(const float4*)&Cpart[(long)z * MN + (long)p * HID + c];
        s.x += q.x; s.y += q.y; s.z += q.z; s.w += q.w;
    }
    float4 bi = *(const float4*)&b2[c];
    float h[4];
    h[0] = fmaxf(s.x + bi.x, 0.0f);
    h[1] = fmaxf(s.y + bi.y, 0.0f);
    h[2] = fmaxf(s.z + bi.z, 0.0f);
    h[3] = fmaxf(s.w + bi.w, 0.0f);
    float a0 = 0.f, a1 = 0.f, a2 = 0.f, a3 = 0.f;
#pragma unroll
    for (int i = 0; i < 4; ++i) {
        float4 w = *(const float4*)&W3[(c + i) * 4];
        a0 += h[i] * w.x; a1 += h[i] * w.y;
        a2 += h[i] * w.z; a3 += h[i] * w.w;
    }
#pragma unroll
    for (int off = 32; off > 0; off >>= 1) {
        a0 += __shfl_down(a0, off);
        a1 += __shfl_down(a1, off);
        a2 += __shfl_down(a2, off);
        a3 += __shfl_down(a3, off);
    }
    if (lane == 0) {
        red[wave][0] = a0; red[wave][1] = a1;
        red[wave][2] = a2; red[wave][3] = a3;
    }
    __syncthreads();
    if (t == 0) {
        int r = (int)cidx[p];
        float d0 = red[0][0] + red[1][0] + red[2][0] + red[3][0] + b3[0];
        float d1 = red[0][1] + red[1][1] + red[2][1] + red[3][1] + b3[1];
        float d2 = red[0][2] + red[1][2] + red[2][2] + red[3][2] + b3[2];
        float d3 = red[0][3] + red[1][3] + red[2][3] + red[3][3] + b3[3];
        float4 b = ((const float4*)sel)[r];
        float acx = b.x + 0.5f * b.z;
        float acy = b.y + 0.5f * b.w;
        float cx = acx + d0 * b.z;
        float cy = acy + d1 * b.w;
        float nw = b.z * expf(d2);
        float nh = b.w * expf(d3);
        out[r * 5 + 0] = cx - 0.5f * nw;
        out[r * 5 + 1] = cy - 0.5f * nh;
        out[r * 5 + 2] = nw;
        out[r * 5 + 3] = nh;
        out[r * 5 + 4] = top_score[r];        // kept implies valid
    }
}

// ---------------------------------------------------------------- host
extern "C" void kernel_launch(void* const* d_in, const int* in_sizes, int n_in,
                              void* d_out, int out_size, void* d_ws, size_t ws_size,
                              hipStream_t stream) {
    const float* features = (const float*)d_in[0];
    const float* rpn_obj  = (const float*)d_in[1];
    const float* rpn_reg  = (const float*)d_in[2];
    const float* anchors  = (const float*)d_in[3];
    const float* W1 = (const float*)d_in[4];
    const float* b1 = (const float*)d_in[5];
    const float* W2 = (const float*)d_in[6];
    const float* b2 = (const float*)d_in[7];
    const float* W3 = (const float*)d_in[8];
    const float* b3 = (const float*)d_in[9];
    float* out = (float*)d_out;

    char* ws = (char*)d_ws;
    size_t off = 0;
    auto alloc = [&](size_t bytes) {
        char* p = ws + off;
        off += (bytes + 255) & ~(size_t)255;
        return p;
    };
    unsigned* hist      = (unsigned*)alloc(NBUCK * sizeof(unsigned));
    unsigned long long* bins =
        (unsigned long long*)alloc((size_t)NBUCK * BINCAP * 8);
    float*    sel       = (float*)alloc(MAXD * 4 * sizeof(float));
    float*    top_score = (float*)alloc(MAXD * sizeof(float));
    unsigned* valid     = (unsigned*)alloc(MAXD * sizeof(unsigned));
    unsigned* cidx      = (unsigned*)alloc(MAXD * sizeof(unsigned));
    unsigned* nkeep     = (unsigned*)alloc(sizeof(unsigned));
    unsigned long long* mask = (unsigned long long*)alloc(MAXD * 8 * 8);
    unsigned short* pooled = (unsigned short*)alloc((size_t)MAXD * FIN * 2);
    unsigned short* W1t = (unsigned short*)alloc((size_t)FIN * HID * 2);
    unsigned short* W2t = (unsigned short*)alloc((size_t)HID * HID * 2);
    unsigned short* h1  = (unsigned short*)alloc((size_t)MAXD * HID * 2);
    float*    Cpart     = (float*)alloc((size_t)SPLITK * MAXD * HID * sizeof(float));
    (void)ws_size; (void)in_sizes; (void)n_in;

    hipMemsetAsync(hist, 0, NBUCK * sizeof(unsigned), stream);
    hipMemsetAsync(out, 0, (size_t)out_size * sizeof(float), stream);

    const int TBLOCKS = (FIN / 32) * (HID / 32) + (HID / 32) * (HID / 32);
    front_kernel<<<256 + TBLOCKS, 256, 0, stream>>>(rpn_obj, hist, bins,
                                                    W1, W1t, W2, W2t);
    tgs_kernel<<<1, 1024, 0, stream>>>(hist, bins, rpn_reg, anchors,
                                       sel, top_score, valid);
    iou_mask_kernel<<<MAXD, 512, 0, stream>>>(sel, mask);
    nms_scan_kernel<<<1, 64, 0, stream>>>(mask, valid, cidx, nkeep);
    roialign_kernel<<<MAXD, 256, 0, stream>>>(features, sel, cidx, nkeep,
                                              pooled);

    const int MN = MAXD * HID;
    // GEMM1: pooled(P x 4608) @ W1 -> Cpart, reduce+b1+relu -> h1 (bf16)
    mfma_gemm_kernel<<<dim3(HID / 64, MAXD / 64, SPLITK), 256, 0, stream>>>(
        pooled, W1t, Cpart, nkeep, MAXD, HID, FIN);
    reduce_bias_relu_kernel<<<MN / 4 / 256, 256, 0, stream>>>(
        Cpart, b1, h1, nkeep, MN, HID);
    // GEMM2: h1(P x 1024) @ W2 -> Cpart; rowhead reduces + b2 + relu + W3
    mfma_gemm_kernel<<<dim3(HID / 64, MAXD / 64, SPLITK), 256, 0, stream>>>(
        h1, W2t, Cpart, nkeep, MAXD, HID, HID);
    rowhead_kernel<<<MAXD, 256, 0, stream>>>(Cpart, b2, W3, b3, sel,
                                             top_score, cidx, nkeep, out);
}